// Round 2
// 1723.043 us; speedup vs baseline: 1.0717x; 1.0717x over previous
//
#include <hip/hip_runtime.h>
#include <cstdint>
#include <cstddef>

// Problem constants (fixed shapes from reference)
#define T_TOK 2048
#define HD    2880
#define ID    2880
#define NE    8
#define TOPK  4
#define ALPHA 1.702f
#define LIMIT 7.0f

typedef __attribute__((ext_vector_type(8))) short short8;   // 8 bf16 in 4 VGPRs
typedef __attribute__((ext_vector_type(4))) float floatx4;  // MFMA C/D frag

__device__ __forceinline__ ushort f32_bf16(float f) {
    union { float f; uint32_t u; } c; c.f = f;
    uint32_t u = c.u;
    uint32_t r = (u + 0x7FFFu + ((u >> 16) & 1u)) >> 16;  // RNE
    return (ushort)r;
}

// async global->LDS, 16B per lane. LDS side must be wave-uniform base + lane*16
// (linear layout); global side may be per-lane scattered (token gather is OK).
__device__ __forceinline__ void gload_lds16(const void* g, void* l) {
    __builtin_amdgcn_global_load_lds(
        (const __attribute__((address_space(1))) void*)g,
        (__attribute__((address_space(3))) void*)l,
        16, 0, 0);
}

// ---------------------------------------------------------------- cvt x -> bf16
__global__ __launch_bounds__(256) void cvt_x_kernel(const float* __restrict__ x,
                                                    ushort* __restrict__ xb) {
    int i = (blockIdx.x * 256 + threadIdx.x) * 4;
    float4 v = *(const float4*)(x + i);
    ushort4 o;
    o.x = f32_bf16(v.x); o.y = f32_bf16(v.y);
    o.z = f32_bf16(v.z); o.w = f32_bf16(v.w);
    *(ushort4*)(xb + i) = o;
}

// ---------------------------------------------------------------- cvt weights -> bf16 (once)
__global__ __launch_bounds__(256) void cvt_w_kernel(const float* __restrict__ w,
                                                    ushort* __restrict__ wb, int n4) {
    int stride = gridDim.x * 256;
    for (int i = blockIdx.x * 256 + threadIdx.x; i < n4; i += stride) {
        float4 v = *(const float4*)(w + (size_t)i * 4);
        ushort4 o;
        o.x = f32_bf16(v.x); o.y = f32_bf16(v.y);
        o.z = f32_bf16(v.z); o.w = f32_bf16(v.w);
        *(ushort4*)(wb + (size_t)i * 4) = o;
    }
}

// ---------------------------------------------------------------- router (fp32)
__global__ __launch_bounds__(256) void router_kernel(
    const float* __restrict__ x, const float* __restrict__ wr,
    const float* __restrict__ br, int* __restrict__ cnt,
    int* __restrict__ tok_list, float* __restrict__ wgt_list) {
    const int t = blockIdx.x, tid = threadIdx.x;
    __shared__ float sx[HD];
    __shared__ float sred[NE][4];
    for (int h = tid; h < HD; h += 256) sx[h] = x[(size_t)t * HD + h];
    __syncthreads();
    float p[NE];
#pragma unroll
    for (int e = 0; e < NE; e++) p[e] = 0.f;
    for (int h = tid; h < HD; h += 256) {
        float xv = sx[h];
#pragma unroll
        for (int e = 0; e < NE; e++) p[e] = fmaf(xv, wr[e * HD + h], p[e]);
    }
#pragma unroll
    for (int e = 0; e < NE; e++) {
#pragma unroll
        for (int off = 32; off > 0; off >>= 1) p[e] += __shfl_down(p[e], off, 64);
    }
    if ((tid & 63) == 0) {
#pragma unroll
        for (int e = 0; e < NE; e++) sred[e][tid >> 6] = p[e];
    }
    __syncthreads();
    if (tid == 0) {
        float lg[NE];
#pragma unroll
        for (int e = 0; e < NE; e++)
            lg[e] = sred[e][0] + sred[e][1] + sred[e][2] + sred[e][3] + br[e];
        int idx[TOPK]; float val[TOPK];
        unsigned used = 0;
#pragma unroll
        for (int k = 0; k < TOPK; k++) {
            int best = -1; float bv = -1e30f;
#pragma unroll
            for (int e = 0; e < NE; e++) {
                if (!((used >> e) & 1u) && lg[e] > bv) { bv = lg[e]; best = e; }
            }
            used |= 1u << best; idx[k] = best; val[k] = bv;
        }
        float m = val[0];  // descending order -> val[0] is max
        float ex[TOPK], s = 0.f;
#pragma unroll
        for (int k = 0; k < TOPK; k++) { ex[k] = __expf(val[k] - m); s += ex[k]; }
        float inv = 1.f / s;
#pragma unroll
        for (int k = 0; k < TOPK; k++) {
            int e = idx[k];
            int pos = atomicAdd(&cnt[e], 1);
            tok_list[e * T_TOK + pos] = t;
            wgt_list[e * T_TOK + pos] = ex[k] * inv;
        }
    }
}

// ---------------------------------------------------------------- prefix offsets
__global__ void offsets_kernel(const int* __restrict__ cnt, int* __restrict__ ofs) {
    if (threadIdx.x == 0 && blockIdx.x == 0) {
        int s = 0;
        for (int e = 0; e < NE; e++) { ofs[e] = s; s += cnt[e]; }
    }
}

// ================================================================ NEW PATH
// m97-style 128x128, BK=32, 4 waves x (64x64), global_load_lds(16B), linear LDS.

// ---- stage 1: gate+up+act (bf16 weights)
__global__ __launch_bounds__(256, 2) void expert_gu2_kernel(
    const ushort* __restrict__ xb, const ushort* __restrict__ wgb,
    const float* __restrict__ bg, const ushort* __restrict__ wub,
    const float* __restrict__ bu, const int* __restrict__ cnt,
    const int* __restrict__ ofs, const int* __restrict__ tok_list,
    ushort* __restrict__ act) {
    const int e = blockIdx.z;
    const int n_e = cnt[e];
    const int mBase = blockIdx.y * 128;
    if (mBase >= n_e) return;
    const int nBase = blockIdx.x * 128;
    const int tid = threadIdx.x;

    __shared__ __attribute__((aligned(16))) ushort sA[128 * 32];
    __shared__ __attribute__((aligned(16))) ushort sBg[128 * 32];
    __shared__ __attribute__((aligned(16))) ushort sBu[128 * 32];
    __shared__ int sTok[128];

    if (tid < 128) {
        int slot = mBase + tid;
        sTok[tid] = tok_list[e * T_TOK + (slot < n_e ? slot : 0)];
    }
    __syncthreads();

    // per-lane global source pointers (row fixed across k-loop; add k0 each step)
    const ushort* wgE = wgb + (size_t)e * (size_t)ID * HD;
    const ushort* wuE = wub + (size_t)e * (size_t)ID * HD;
    const ushort* aSrc[2];
    const ushort* gSrc[2];
    const ushort* uSrc[2];
#pragma unroll
    for (int i = 0; i < 2; i++) {
        int lin = i * 256 + tid;          // 512 x 16B covers 128x32 bf16
        int ar = lin >> 2, ac = lin & 3;  // 4 lanes per 64B row
        aSrc[i] = xb + (size_t)sTok[ar] * HD + ac * 8;
        int n = nBase + ar; if (n >= ID) n = ID - 1;
        gSrc[i] = wgE + (size_t)n * HD + ac * 8;
        uSrc[i] = wuE + (size_t)n * HD + ac * 8;
    }

    const int wave = tid >> 6, lane = tid & 63;
    const int wm = (wave >> 1) * 64, wn = (wave & 1) * 64;
    const int ln = lane & 15, quad = lane >> 4;

    floatx4 accG[4][4], accU[4][4];
#pragma unroll
    for (int mi = 0; mi < 4; mi++)
#pragma unroll
        for (int ni = 0; ni < 4; ni++) {
            accG[mi][ni] = (floatx4){0.f, 0.f, 0.f, 0.f};
            accU[mi][ni] = (floatx4){0.f, 0.f, 0.f, 0.f};
        }

    for (int k0 = 0; k0 < HD; k0 += 32) {
#pragma unroll
        for (int i = 0; i < 2; i++) {
            int lin = i * 256 + tid;
            gload_lds16(aSrc[i] + k0, &sA[lin * 8]);
            gload_lds16(gSrc[i] + k0, &sBg[lin * 8]);
            gload_lds16(uSrc[i] + k0, &sBu[lin * 8]);
        }
        __syncthreads();  // compiler emits vmcnt(0) drain before barrier

        short8 af[4], bgf[4], buf_[4];
#pragma unroll
        for (int mi = 0; mi < 4; mi++)
            af[mi] = *(const short8*)&sA[(wm + mi * 16 + ln) * 32 + quad * 8];
#pragma unroll
        for (int ni = 0; ni < 4; ni++) {
            bgf[ni] = *(const short8*)&sBg[(wn + ni * 16 + ln) * 32 + quad * 8];
            buf_[ni] = *(const short8*)&sBu[(wn + ni * 16 + ln) * 32 + quad * 8];
        }
#pragma unroll
        for (int mi = 0; mi < 4; mi++)
#pragma unroll
            for (int ni = 0; ni < 4; ni++) {
                accG[mi][ni] = __builtin_amdgcn_mfma_f32_16x16x32_bf16(
                    af[mi], bgf[ni], accG[mi][ni], 0, 0, 0);
                accU[mi][ni] = __builtin_amdgcn_mfma_f32_16x16x32_bf16(
                    af[mi], buf_[ni], accU[mi][ni], 0, 0, 0);
            }
        __syncthreads();
    }

    // epilogue: bias + clamp + swiglu, store bf16 act
    const int row0 = ofs[e] + mBase;
#pragma unroll
    for (int mi = 0; mi < 4; mi++) {
#pragma unroll
        for (int r = 0; r < 4; r++) {
            int ml = wm + mi * 16 + quad * 4 + r;
            if (mBase + ml >= n_e) continue;
#pragma unroll
            for (int ni = 0; ni < 4; ni++) {
                int n = nBase + wn + ni * 16 + ln;
                if (n < ID) {
                    float g = accG[mi][ni][r] + bg[e * ID + n];
                    float u = accU[mi][ni][r] + bu[e * ID + n];
                    g = fminf(g, LIMIT);
                    u = fminf(fmaxf(u, -LIMIT), LIMIT);
                    float sg = 1.0f / (1.0f + __expf(-ALPHA * g));
                    float a = (u + 1.0f) * (g * sg);
                    act[(size_t)(row0 + ml) * ID + n] = f32_bf16(a);
                }
            }
        }
    }
}

// ---- stage 2: down proj (bf16 weights)
__global__ __launch_bounds__(256, 2) void expert_down2_kernel(
    const ushort* __restrict__ act, const ushort* __restrict__ w2b,
    const float* __restrict__ b2, const int* __restrict__ cnt,
    const int* __restrict__ ofs, const int* __restrict__ tok_list,
    const float* __restrict__ wgt_list, float* __restrict__ out) {
    const int e = blockIdx.z;
    const int n_e = cnt[e];
    const int mBase = blockIdx.y * 128;
    if (mBase >= n_e) return;
    const int nBase = blockIdx.x * 128;
    const int tid = threadIdx.x;

    __shared__ __attribute__((aligned(16))) ushort sA[128 * 32];
    __shared__ __attribute__((aligned(16))) ushort sB[128 * 32];
    __shared__ int sTok[128];
    __shared__ float sWgt[128];

    if (tid < 128) {
        int slot = mBase + tid;
        int cs = (slot < n_e) ? slot : 0;
        sTok[tid] = tok_list[e * T_TOK + cs];
        sWgt[tid] = wgt_list[e * T_TOK + cs];
    }
    __syncthreads();

    const int row0 = ofs[e] + mBase;
    const ushort* w2E = w2b + (size_t)e * (size_t)HD * ID;
    const ushort* aSrc[2];
    const ushort* bSrc[2];
#pragma unroll
    for (int i = 0; i < 2; i++) {
        int lin = i * 256 + tid;
        int ar = lin >> 2, ac = lin & 3;
        int rr = (mBase + ar < n_e) ? ar : 0;  // stay inside packed act
        aSrc[i] = act + (size_t)(row0 + rr) * ID + ac * 8;
        int n = nBase + ar; if (n >= HD) n = HD - 1;
        bSrc[i] = w2E + (size_t)n * ID + ac * 8;
    }

    const int wave = tid >> 6, lane = tid & 63;
    const int wm = (wave >> 1) * 64, wn = (wave & 1) * 64;
    const int ln = lane & 15, quad = lane >> 4;

    floatx4 acc[4][4];
#pragma unroll
    for (int mi = 0; mi < 4; mi++)
#pragma unroll
        for (int ni = 0; ni < 4; ni++) acc[mi][ni] = (floatx4){0.f, 0.f, 0.f, 0.f};

    for (int k0 = 0; k0 < ID; k0 += 32) {
#pragma unroll
        for (int i = 0; i < 2; i++) {
            int lin = i * 256 + tid;
            gload_lds16(aSrc[i] + k0, &sA[lin * 8]);
            gload_lds16(bSrc[i] + k0, &sB[lin * 8]);
        }
        __syncthreads();

        short8 af[4], bf[4];
#pragma unroll
        for (int mi = 0; mi < 4; mi++)
            af[mi] = *(const short8*)&sA[(wm + mi * 16 + ln) * 32 + quad * 8];
#pragma unroll
        for (int ni = 0; ni < 4; ni++)
            bf[ni] = *(const short8*)&sB[(wn + ni * 16 + ln) * 32 + quad * 8];
#pragma unroll
        for (int mi = 0; mi < 4; mi++)
#pragma unroll
            for (int ni = 0; ni < 4; ni++)
                acc[mi][ni] = __builtin_amdgcn_mfma_f32_16x16x32_bf16(
                    af[mi], bf[ni], acc[mi][ni], 0, 0, 0);
        __syncthreads();
    }

#pragma unroll
    for (int mi = 0; mi < 4; mi++) {
#pragma unroll
        for (int r = 0; r < 4; r++) {
            int ml = wm + mi * 16 + quad * 4 + r;
            if (mBase + ml >= n_e) continue;
            int token = sTok[ml];
            float wgt = sWgt[ml];
#pragma unroll
            for (int ni = 0; ni < 4; ni++) {
                int n = nBase + wn + ni * 16 + ln;
                if (n < HD) {
                    float v = (acc[mi][ni][r] + b2[e * HD + n]) * wgt;
                    atomicAdd(&out[(size_t)token * HD + n], v);
                }
            }
        }
    }
}

// ================================================================ FALLBACK PATH
// (previous verified fp32-weight kernels; used only if workspace is too small)
#define LDS_S 40  // padded row stride in bf16 elems
__global__ __launch_bounds__(256, 2) void expert_gu_kernel(
    const ushort* __restrict__ xb, const float* __restrict__ wg,
    const float* __restrict__ bg, const float* __restrict__ wu,
    const float* __restrict__ bu, const int* __restrict__ cnt,
    const int* __restrict__ ofs, const int* __restrict__ tok_list,
    ushort* __restrict__ act) {
    const int e = blockIdx.z;
    const int n_e = cnt[e];
    const int mBase = blockIdx.y * 128;
    if (mBase >= n_e) return;
    const int nBase = blockIdx.x * 128;
    const int tid = threadIdx.x;

    __shared__ ushort sA[128 * LDS_S];
    __shared__ ushort sBg[128 * LDS_S];
    __shared__ ushort sBu[128 * LDS_S];
    __shared__ int sTok[128];

    if (tid < 128) {
        int slot = mBase + tid;
        sTok[tid] = tok_list[e * T_TOK + (slot < n_e ? slot : 0)];
    }
    __syncthreads();

    const int wave = tid >> 6, lane = tid & 63;
    const int wm = (wave >> 1) * 64, wn = (wave & 1) * 64;
    const int ln = lane & 15, quad = lane >> 4;

    floatx4 accG[4][4], accU[4][4];
#pragma unroll
    for (int mi = 0; mi < 4; mi++)
#pragma unroll
        for (int ni = 0; ni < 4; ni++) {
            accG[mi][ni] = (floatx4){0.f, 0.f, 0.f, 0.f};
            accU[mi][ni] = (floatx4){0.f, 0.f, 0.f, 0.f};
        }

    const float* wgE = wg + (size_t)e * ID * HD;
    const float* wuE = wu + (size_t)e * ID * HD;

    for (int k0 = 0; k0 < HD; k0 += 32) {
#pragma unroll
        for (int r = 0; r < 2; r++) {
            int lin = r * 256 + tid;
            int ar = lin >> 2, ac = lin & 3;
            uint4 v = *(const uint4*)(xb + (size_t)sTok[ar] * HD + k0 + ac * 8);
            *(uint4*)&sA[ar * LDS_S + ac * 8] = v;
        }
#pragma unroll
        for (int r = 0; r < 4; r++) {
            int c = r * 256 + tid;
            int brow = c >> 3, bc = c & 7;
            int n = nBase + brow; if (n >= ID) n = ID - 1;
            float4 g4 = *(const float4*)(wgE + (size_t)n * HD + k0 + bc * 4);
            float4 u4 = *(const float4*)(wuE + (size_t)n * HD + k0 + bc * 4);
            ushort4 gg, uu;
            gg.x = f32_bf16(g4.x); gg.y = f32_bf16(g4.y);
            gg.z = f32_bf16(g4.z); gg.w = f32_bf16(g4.w);
            uu.x = f32_bf16(u4.x); uu.y = f32_bf16(u4.y);
            uu.z = f32_bf16(u4.z); uu.w = f32_bf16(u4.w);
            *(ushort4*)&sBg[brow * LDS_S + bc * 4] = gg;
            *(ushort4*)&sBu[brow * LDS_S + bc * 4] = uu;
        }
        __syncthreads();
        short8 af[4], bgf[4], buf_[4];
#pragma unroll
        for (int mi = 0; mi < 4; mi++)
            af[mi] = *(const short8*)&sA[(wm + mi * 16 + ln) * LDS_S + quad * 8];
#pragma unroll
        for (int ni = 0; ni < 4; ni++) {
            bgf[ni] = *(const short8*)&sBg[(wn + ni * 16 + ln) * LDS_S + quad * 8];
            buf_[ni] = *(const short8*)&sBu[(wn + ni * 16 + ln) * LDS_S + quad * 8];
        }
#pragma unroll
        for (int mi = 0; mi < 4; mi++)
#pragma unroll
            for (int ni = 0; ni < 4; ni++) {
                accG[mi][ni] = __builtin_amdgcn_mfma_f32_16x16x32_bf16(
                    af[mi], bgf[ni], accG[mi][ni], 0, 0, 0);
                accU[mi][ni] = __builtin_amdgcn_mfma_f32_16x16x32_bf16(
                    af[mi], buf_[ni], accU[mi][ni], 0, 0, 0);
            }
        __syncthreads();
    }

    const int row0 = ofs[e] + mBase;
#pragma unroll
    for (int mi = 0; mi < 4; mi++) {
#pragma unroll
        for (int r = 0; r < 4; r++) {
            int ml = wm + mi * 16 + quad * 4 + r;
            if (mBase + ml >= n_e) continue;
#pragma unroll
            for (int ni = 0; ni < 4; ni++) {
                int n = nBase + wn + ni * 16 + ln;
                if (n < ID) {
                    float g = accG[mi][ni][r] + bg[e * ID + n];
                    float u = accU[mi][ni][r] + bu[e * ID + n];
                    g = fminf(g, LIMIT);
                    u = fminf(fmaxf(u, -LIMIT), LIMIT);
                    float sg = 1.0f / (1.0f + __expf(-ALPHA * g));
                    float a = (u + 1.0f) * (g * sg);
                    act[(size_t)(row0 + ml) * ID + n] = f32_bf16(a);
                }
            }
        }
    }
}

__global__ __launch_bounds__(256, 2) void expert_down_kernel(
    const ushort* __restrict__ act, const float* __restrict__ w2,
    const float* __restrict__ b2, const int* __restrict__ cnt,
    const int* __restrict__ ofs, const int* __restrict__ tok_list,
    const float* __restrict__ wgt_list, float* __restrict__ out) {
    const int e = blockIdx.z;
    const int n_e = cnt[e];
    const int mBase = blockIdx.y * 128;
    if (mBase >= n_e) return;
    const int nBase = blockIdx.x * 128;
    const int tid = threadIdx.x;

    __shared__ ushort sA[128 * LDS_S];
    __shared__ ushort sB[128 * LDS_S];
    __shared__ int sTok[128];
    __shared__ float sWgt[128];

    if (tid < 128) {
        int slot = mBase + tid;
        int cs = (slot < n_e) ? slot : 0;
        sTok[tid] = tok_list[e * T_TOK + cs];
        sWgt[tid] = wgt_list[e * T_TOK + cs];
    }
    __syncthreads();

    const int wave = tid >> 6, lane = tid & 63;
    const int wm = (wave >> 1) * 64, wn = (wave & 1) * 64;
    const int ln = lane & 15, quad = lane >> 4;
    const int row0 = ofs[e] + mBase;

    floatx4 acc[4][4];
#pragma unroll
    for (int mi = 0; mi < 4; mi++)
#pragma unroll
        for (int ni = 0; ni < 4; ni++) acc[mi][ni] = (floatx4){0.f, 0.f, 0.f, 0.f};

    const float* w2E = w2 + (size_t)e * HD * ID;

    for (int k0 = 0; k0 < ID; k0 += 32) {
#pragma unroll
        for (int r = 0; r < 2; r++) {
            int lin = r * 256 + tid;
            int ar = lin >> 2, ac = lin & 3;
            int rr = (mBase + ar < n_e) ? ar : 0;
            uint4 v = *(const uint4*)(act + (size_t)(row0 + rr) * ID + k0 + ac * 8);
            *(uint4*)&sA[ar * LDS_S + ac * 8] = v;
        }
#pragma unroll
        for (int r = 0; r < 4; r++) {
            int c = r * 256 + tid;
            int brow = c >> 3, bc = c & 7;
            int n = nBase + brow; if (n >= HD) n = HD - 1;
            float4 b4 = *(const float4*)(w2E + (size_t)n * ID + k0 + bc * 4);
            ushort4 bb;
            bb.x = f32_bf16(b4.x); bb.y = f32_bf16(b4.y);
            bb.z = f32_bf16(b4.z); bb.w = f32_bf16(b4.w);
            *(ushort4*)&sB[brow * LDS_S + bc * 4] = bb;
        }
        __syncthreads();
        short8 af[4], bf[4];
#pragma unroll
        for (int mi = 0; mi < 4; mi++)
            af[mi] = *(const short8*)&sA[(wm + mi * 16 + ln) * LDS_S + quad * 8];
#pragma unroll
        for (int ni = 0; ni < 4; ni++)
            bf[ni] = *(const short8*)&sB[(wn + ni * 16 + ln) * LDS_S + quad * 8];
#pragma unroll
        for (int mi = 0; mi < 4; mi++)
#pragma unroll
            for (int ni = 0; ni < 4; ni++)
                acc[mi][ni] = __builtin_amdgcn_mfma_f32_16x16x32_bf16(
                    af[mi], bf[ni], acc[mi][ni], 0, 0, 0);
        __syncthreads();
    }

#pragma unroll
    for (int mi = 0; mi < 4; mi++) {
#pragma unroll
        for (int r = 0; r < 4; r++) {
            int ml = wm + mi * 16 + quad * 4 + r;
            if (mBase + ml >= n_e) continue;
            int token = sTok[ml];
            float wgt = sWgt[ml];
#pragma unroll
            for (int ni = 0; ni < 4; ni++) {
                int n = nBase + wn + ni * 16 + ln;
                if (n < HD) {
                    float v = (acc[mi][ni][r] + b2[e * HD + n]) * wgt;
                    atomicAdd(&out[(size_t)token * HD + n], v);
                }
            }
        }
    }
}

// ---------------------------------------------------------------- launch
extern "C" void kernel_launch(void* const* d_in, const int* in_sizes, int n_in,
                              void* d_out, int out_size, void* d_ws, size_t ws_size,
                              hipStream_t stream) {
    const float* x  = (const float*)d_in[0];
    const float* wr = (const float*)d_in[1];
    const float* br = (const float*)d_in[2];
    const float* wg = (const float*)d_in[3];
    const float* bg = (const float*)d_in[4];
    const float* wu = (const float*)d_in[5];
    const float* bu = (const float*)d_in[6];
    const float* w2 = (const float*)d_in[7];
    const float* b2 = (const float*)d_in[8];
    float* out = (float*)d_out;

    // workspace layout
    char* ws = (char*)d_ws;
    int*    cnt      = (int*)ws;                        // 32 B used
    int*    ofs      = (int*)(ws + 256);
    int*    tok_list = (int*)(ws + 512);                // E*T*4   = 65536
    float*  wgt_list = (float*)(ws + 512 + 65536);      // E*T*4   = 65536
    ushort* xb       = (ushort*)(ws + 131584);          // T*H*2   = 11796480
    ushort* act      = (ushort*)(ws + 131584 + 11796480);          // 8192*I*2 = 47185920
    // bf16 weight copies (new path only): 3 x 132710400
    const size_t W_ELEMS = (size_t)NE * ID * HD;        // 66,355,200 per tensor
    ushort* wgb = (ushort*)(ws + 59113984);
    ushort* wub = (ushort*)(ws + 59113984 + 132710400);
    ushort* w2b = (ushort*)(ws + 59113984 + 2ull * 132710400);
    const size_t NEED = 59113984ull + 3ull * 132710400ull;  // 457,245,184 B

    hipMemsetAsync(out, 0, (size_t)T_TOK * HD * sizeof(float), stream);
    hipMemsetAsync(cnt, 0, NE * sizeof(int), stream);

    cvt_x_kernel<<<(T_TOK * HD) / 4 / 256, 256, 0, stream>>>(x, xb);
    router_kernel<<<T_TOK, 256, 0, stream>>>(x, wr, br, cnt, tok_list, wgt_list);
    offsets_kernel<<<1, 64, 0, stream>>>(cnt, ofs);

    if (ws_size >= NEED) {
        const int n4 = (int)(W_ELEMS / 4);  // 16,588,800
        cvt_w_kernel<<<8192, 256, 0, stream>>>(wg, wgb, n4);
        cvt_w_kernel<<<8192, 256, 0, stream>>>(wu, wub, n4);
        cvt_w_kernel<<<8192, 256, 0, stream>>>(w2, w2b, n4);

        dim3 g1((ID + 127) / 128, T_TOK / 128, NE);
        expert_gu2_kernel<<<g1, 256, 0, stream>>>(xb, wgb, bg, wub, bu, cnt, ofs,
                                                  tok_list, act);
        dim3 g2((HD + 127) / 128, T_TOK / 128, NE);
        expert_down2_kernel<<<g2, 256, 0, stream>>>(act, w2b, b2, cnt, ofs, tok_list,
                                                    wgt_list, out);
    } else {
        dim3 g1((ID + 127) / 128, T_TOK / 128, NE);
        expert_gu_kernel<<<g1, 256, 0, stream>>>(xb, wg, bg, wu, bu, cnt, ofs,
                                                 tok_list, act);
        dim3 g2((HD + 127) / 128, T_TOK / 128, NE);
        expert_down_kernel<<<g2, 256, 0, stream>>>(act, w2, b2, cnt, ofs, tok_list,
                                                   wgt_list, out);
    }
}

// Round 3
// 1598.553 us; speedup vs baseline: 1.1552x; 1.0779x over previous
//
#include <hip/hip_runtime.h>
#include <cstdint>
#include <cstddef>

// Problem constants (fixed shapes from reference)
#define T_TOK 2048
#define HD    2880
#define ID    2880
#define NE    8
#define TOPK  4
#define ALPHA 1.702f
#define LIMIT 7.0f

// 128x128 block grid geometry (ID==HD==2880 -> 23 n-blocks, 16 m-blocks, 8 experts)
#define NXB 23
#define NYB 16
#define NWG (NXB * NYB * NE)   // 2944 = 8 * 368

typedef __attribute__((ext_vector_type(8))) short short8;   // 8 bf16 in 4 VGPRs
typedef __attribute__((ext_vector_type(4))) float floatx4;  // MFMA C/D frag

__device__ __forceinline__ ushort f32_bf16(float f) {
    union { float f; uint32_t u; } c; c.f = f;
    uint32_t u = c.u;
    uint32_t r = (u + 0x7FFFu + ((u >> 16) & 1u)) >> 16;  // RNE
    return (ushort)r;
}

// async global->LDS, 16B per lane. LDS side must be wave-uniform base + lane*16
// (linear layout); global side may be per-lane scattered (token gather is OK).
__device__ __forceinline__ void gload_lds16(const void* g, void* l) {
    __builtin_amdgcn_global_load_lds(
        (const __attribute__((address_space(1))) void*)g,
        (__attribute__((address_space(3))) void*)l,
        16, 0, 0);
}

// XCD-chunked swizzle: HW bid round-robins over 8 XCDs; this gives each XCD a
// contiguous chunk of the work order. Work order: y (m-block) fastest, then
// expert, then x (n-block) -> the 16 m-blocks sharing one (e,x) weight panel
// (1.47 MB, L2-fits) are consecutive works on one XCD.
__device__ __forceinline__ void decode_work(int b, int& e, int& xq, int& y) {
    int w = (b & 7) * (NWG >> 3) + (b >> 3);
    y = w & 15;
    int rest = w >> 4;        // [0, 184)
    e = rest & 7;
    xq = rest >> 3;           // [0, 23)
}

// ---------------------------------------------------------------- cvt x -> bf16
__global__ __launch_bounds__(256) void cvt_x_kernel(const float* __restrict__ x,
                                                    ushort* __restrict__ xb) {
    int i = (blockIdx.x * 256 + threadIdx.x) * 4;
    float4 v = *(const float4*)(x + i);
    ushort4 o;
    o.x = f32_bf16(v.x); o.y = f32_bf16(v.y);
    o.z = f32_bf16(v.z); o.w = f32_bf16(v.w);
    *(ushort4*)(xb + i) = o;
}

// ---------------------------------------------------------------- cvt weights -> bf16 (once)
__global__ __launch_bounds__(256) void cvt_w_kernel(const float* __restrict__ w,
                                                    ushort* __restrict__ wb, int n4) {
    int stride = gridDim.x * 256;
    for (int i = blockIdx.x * 256 + threadIdx.x; i < n4; i += stride) {
        float4 v = *(const float4*)(w + (size_t)i * 4);
        ushort4 o;
        o.x = f32_bf16(v.x); o.y = f32_bf16(v.y);
        o.z = f32_bf16(v.z); o.w = f32_bf16(v.w);
        *(ushort4*)(wb + (size_t)i * 4) = o;
    }
}

// ---------------------------------------------------------------- router (fp32)
__global__ __launch_bounds__(256) void router_kernel(
    const float* __restrict__ x, const float* __restrict__ wr,
    const float* __restrict__ br, int* __restrict__ cnt,
    int* __restrict__ tok_list, float* __restrict__ wgt_list,
    int* __restrict__ t2s) {
    const int t = blockIdx.x, tid = threadIdx.x;
    __shared__ float sx[HD];
    __shared__ float sred[NE][4];
    for (int h = tid; h < HD; h += 256) sx[h] = x[(size_t)t * HD + h];
    __syncthreads();
    float p[NE];
#pragma unroll
    for (int e = 0; e < NE; e++) p[e] = 0.f;
    for (int h = tid; h < HD; h += 256) {
        float xv = sx[h];
#pragma unroll
        for (int e = 0; e < NE; e++) p[e] = fmaf(xv, wr[e * HD + h], p[e]);
    }
#pragma unroll
    for (int e = 0; e < NE; e++) {
#pragma unroll
        for (int off = 32; off > 0; off >>= 1) p[e] += __shfl_down(p[e], off, 64);
    }
    if ((tid & 63) == 0) {
#pragma unroll
        for (int e = 0; e < NE; e++) sred[e][tid >> 6] = p[e];
    }
    __syncthreads();
    if (tid == 0) {
        float lg[NE];
#pragma unroll
        for (int e = 0; e < NE; e++)
            lg[e] = sred[e][0] + sred[e][1] + sred[e][2] + sred[e][3] + br[e];
        int idx[TOPK]; float val[TOPK];
        unsigned used = 0;
#pragma unroll
        for (int k = 0; k < TOPK; k++) {
            int best = -1; float bv = -1e30f;
#pragma unroll
            for (int e = 0; e < NE; e++) {
                if (!((used >> e) & 1u) && lg[e] > bv) { bv = lg[e]; best = e; }
            }
            used |= 1u << best; idx[k] = best; val[k] = bv;
        }
        float m = val[0];  // descending order -> val[0] is max
        float ex[TOPK], s = 0.f;
#pragma unroll
        for (int k = 0; k < TOPK; k++) { ex[k] = __expf(val[k] - m); s += ex[k]; }
        float inv = 1.f / s;
#pragma unroll
        for (int k = 0; k < TOPK; k++) {
            int e = idx[k];
            int pos = atomicAdd(&cnt[e], 1);
            tok_list[e * T_TOK + pos] = t;
            wgt_list[e * T_TOK + pos] = ex[k] * inv;
            if (t2s) t2s[t * TOPK + k] = e * T_TOK + pos;
        }
    }
}

// ---------------------------------------------------------------- prefix offsets
__global__ void offsets_kernel(const int* __restrict__ cnt, int* __restrict__ ofs) {
    if (threadIdx.x == 0 && blockIdx.x == 0) {
        int s = 0;
        for (int e = 0; e < NE; e++) { ofs[e] = s; s += cnt[e]; }
    }
}

// ================================================================ FAST PATH
// m97-style 128x128, BK=32, 4 waves x (64x64), global_load_lds(16B), linear LDS,
// 1D XCD-chunked swizzled grid.

// ---- stage 1: gate+up+act (bf16 weights)
__global__ __launch_bounds__(256, 2) void expert_gu2_kernel(
    const ushort* __restrict__ xb, const ushort* __restrict__ wgb,
    const float* __restrict__ bg, const ushort* __restrict__ wub,
    const float* __restrict__ bu, const int* __restrict__ cnt,
    const int* __restrict__ ofs, const int* __restrict__ tok_list,
    ushort* __restrict__ act) {
    int e, xq, y;
    decode_work(blockIdx.x, e, xq, y);
    const int n_e = cnt[e];
    const int mBase = y * 128;
    if (mBase >= n_e) return;
    const int nBase = xq * 128;
    const int tid = threadIdx.x;

    __shared__ __attribute__((aligned(16))) ushort sA[128 * 32];
    __shared__ __attribute__((aligned(16))) ushort sBg[128 * 32];
    __shared__ __attribute__((aligned(16))) ushort sBu[128 * 32];
    __shared__ int sTok[128];

    if (tid < 128) {
        int slot = mBase + tid;
        sTok[tid] = tok_list[e * T_TOK + (slot < n_e ? slot : 0)];
    }
    __syncthreads();

    // per-lane global source pointers (row fixed across k-loop; add k0 each step)
    const ushort* wgE = wgb + (size_t)e * (size_t)ID * HD;
    const ushort* wuE = wub + (size_t)e * (size_t)ID * HD;
    const ushort* aSrc[2];
    const ushort* gSrc[2];
    const ushort* uSrc[2];
#pragma unroll
    for (int i = 0; i < 2; i++) {
        int lin = i * 256 + tid;          // 512 x 16B covers 128x32 bf16
        int ar = lin >> 2, ac = lin & 3;  // 4 lanes per 64B row
        aSrc[i] = xb + (size_t)sTok[ar] * HD + ac * 8;
        int n = nBase + ar; if (n >= ID) n = ID - 1;
        gSrc[i] = wgE + (size_t)n * HD + ac * 8;
        uSrc[i] = wuE + (size_t)n * HD + ac * 8;
    }

    const int wave = tid >> 6, lane = tid & 63;
    const int wm = (wave >> 1) * 64, wn = (wave & 1) * 64;
    const int ln = lane & 15, quad = lane >> 4;

    floatx4 accG[4][4], accU[4][4];
#pragma unroll
    for (int mi = 0; mi < 4; mi++)
#pragma unroll
        for (int ni = 0; ni < 4; ni++) {
            accG[mi][ni] = (floatx4){0.f, 0.f, 0.f, 0.f};
            accU[mi][ni] = (floatx4){0.f, 0.f, 0.f, 0.f};
        }

    for (int k0 = 0; k0 < HD; k0 += 32) {
#pragma unroll
        for (int i = 0; i < 2; i++) {
            int lin = i * 256 + tid;
            gload_lds16(aSrc[i] + k0, &sA[lin * 8]);
            gload_lds16(gSrc[i] + k0, &sBg[lin * 8]);
            gload_lds16(uSrc[i] + k0, &sBu[lin * 8]);
        }
        __syncthreads();  // compiler emits vmcnt(0) drain before barrier

        short8 af[4], bgf[4], buf_[4];
#pragma unroll
        for (int mi = 0; mi < 4; mi++)
            af[mi] = *(const short8*)&sA[(wm + mi * 16 + ln) * 32 + quad * 8];
#pragma unroll
        for (int ni = 0; ni < 4; ni++) {
            bgf[ni] = *(const short8*)&sBg[(wn + ni * 16 + ln) * 32 + quad * 8];
            buf_[ni] = *(const short8*)&sBu[(wn + ni * 16 + ln) * 32 + quad * 8];
        }
#pragma unroll
        for (int mi = 0; mi < 4; mi++)
#pragma unroll
            for (int ni = 0; ni < 4; ni++) {
                accG[mi][ni] = __builtin_amdgcn_mfma_f32_16x16x32_bf16(
                    af[mi], bgf[ni], accG[mi][ni], 0, 0, 0);
                accU[mi][ni] = __builtin_amdgcn_mfma_f32_16x16x32_bf16(
                    af[mi], buf_[ni], accU[mi][ni], 0, 0, 0);
            }
        __syncthreads();
    }

    // epilogue: bias + clamp + swiglu, store bf16 act
    const int row0 = ofs[e] + mBase;
#pragma unroll
    for (int mi = 0; mi < 4; mi++) {
#pragma unroll
        for (int r = 0; r < 4; r++) {
            int ml = wm + mi * 16 + quad * 4 + r;
            if (mBase + ml >= n_e) continue;
#pragma unroll
            for (int ni = 0; ni < 4; ni++) {
                int n = nBase + wn + ni * 16 + ln;
                if (n < ID) {
                    float g = accG[mi][ni][r] + bg[e * ID + n];
                    float u = accU[mi][ni][r] + bu[e * ID + n];
                    g = fminf(g, LIMIT);
                    u = fminf(fmaxf(u, -LIMIT), LIMIT);
                    float sg = 1.0f / (1.0f + __expf(-ALPHA * g));
                    float a = (u + 1.0f) * (g * sg);
                    act[(size_t)(row0 + ml) * ID + n] = f32_bf16(a);
                }
            }
        }
    }
}

// ---- stage 2: down proj, NO atomics. Writes weighted rows to packed y buffer.
__global__ __launch_bounds__(256, 2) void expert_down2_na_kernel(
    const ushort* __restrict__ act, const ushort* __restrict__ w2b,
    const float* __restrict__ b2, const int* __restrict__ cnt,
    const int* __restrict__ ofs, const float* __restrict__ wgt_list,
    float* __restrict__ yws) {
    int e, xq, y;
    decode_work(blockIdx.x, e, xq, y);
    const int n_e = cnt[e];
    const int mBase = y * 128;
    if (mBase >= n_e) return;
    const int nBase = xq * 128;
    const int tid = threadIdx.x;

    __shared__ __attribute__((aligned(16))) ushort sA[128 * 32];
    __shared__ __attribute__((aligned(16))) ushort sB[128 * 32];
    __shared__ float sWgt[128];

    if (tid < 128) {
        int slot = mBase + tid;
        int cs = (slot < n_e) ? slot : 0;
        sWgt[tid] = wgt_list[e * T_TOK + cs];
    }
    __syncthreads();

    const int row0 = ofs[e] + mBase;
    const ushort* w2E = w2b + (size_t)e * (size_t)HD * ID;
    const ushort* aSrc[2];
    const ushort* bSrc[2];
#pragma unroll
    for (int i = 0; i < 2; i++) {
        int lin = i * 256 + tid;
        int ar = lin >> 2, ac = lin & 3;
        int rr = (mBase + ar < n_e) ? ar : 0;  // stay inside packed act
        aSrc[i] = act + (size_t)(row0 + rr) * ID + ac * 8;
        int n = nBase + ar; if (n >= HD) n = HD - 1;
        bSrc[i] = w2E + (size_t)n * ID + ac * 8;
    }

    const int wave = tid >> 6, lane = tid & 63;
    const int wm = (wave >> 1) * 64, wn = (wave & 1) * 64;
    const int ln = lane & 15, quad = lane >> 4;

    floatx4 acc[4][4];
#pragma unroll
    for (int mi = 0; mi < 4; mi++)
#pragma unroll
        for (int ni = 0; ni < 4; ni++) acc[mi][ni] = (floatx4){0.f, 0.f, 0.f, 0.f};

    for (int k0 = 0; k0 < ID; k0 += 32) {
#pragma unroll
        for (int i = 0; i < 2; i++) {
            int lin = i * 256 + tid;
            gload_lds16(aSrc[i] + k0, &sA[lin * 8]);
            gload_lds16(bSrc[i] + k0, &sB[lin * 8]);
        }
        __syncthreads();

        short8 af[4], bf[4];
#pragma unroll
        for (int mi = 0; mi < 4; mi++)
            af[mi] = *(const short8*)&sA[(wm + mi * 16 + ln) * 32 + quad * 8];
#pragma unroll
        for (int ni = 0; ni < 4; ni++)
            bf[ni] = *(const short8*)&sB[(wn + ni * 16 + ln) * 32 + quad * 8];
#pragma unroll
        for (int mi = 0; mi < 4; mi++)
#pragma unroll
            for (int ni = 0; ni < 4; ni++)
                acc[mi][ni] = __builtin_amdgcn_mfma_f32_16x16x32_bf16(
                    af[mi], bf[ni], acc[mi][ni], 0, 0, 0);
        __syncthreads();
    }

#pragma unroll
    for (int mi = 0; mi < 4; mi++) {
#pragma unroll
        for (int r = 0; r < 4; r++) {
            int ml = wm + mi * 16 + quad * 4 + r;
            if (mBase + ml >= n_e) continue;
            float wgt = sWgt[ml];
#pragma unroll
            for (int ni = 0; ni < 4; ni++) {
                int n = nBase + wn + ni * 16 + ln;
                if (n < HD) {
                    yws[(size_t)(row0 + ml) * HD + n] =
                        (acc[mi][ni][r] + b2[e * HD + n]) * wgt;
                }
            }
        }
    }
}

// ---- combine: out[t] = sum_k y[row(t,k)]  (vectorized, no atomics)
__global__ __launch_bounds__(256) void combine_kernel(
    const float* __restrict__ yws, const int* __restrict__ t2s,
    const int* __restrict__ ofs, float* __restrict__ out) {
    const int t = blockIdx.x, tid = threadIdx.x;
    int rows[TOPK];
#pragma unroll
    for (int k = 0; k < TOPK; k++) {
        int slot = t2s[t * TOPK + k];
        rows[k] = ofs[slot >> 11] + (slot & (T_TOK - 1));  // T_TOK = 2048
    }
    for (int i = tid; i < HD / 4; i += 256) {  // 720 float4 per row
        float4 s = *(const float4*)(yws + (size_t)rows[0] * HD + i * 4);
#pragma unroll
        for (int k = 1; k < TOPK; k++) {
            float4 v = *(const float4*)(yws + (size_t)rows[k] * HD + i * 4);
            s.x += v.x; s.y += v.y; s.z += v.z; s.w += v.w;
        }
        *(float4*)(out + (size_t)t * HD + i * 4) = s;
    }
}

// ---- stage 2 (tier-2): down proj with atomics (round-2 verified path)
__global__ __launch_bounds__(256, 2) void expert_down2_kernel(
    const ushort* __restrict__ act, const ushort* __restrict__ w2b,
    const float* __restrict__ b2, const int* __restrict__ cnt,
    const int* __restrict__ ofs, const int* __restrict__ tok_list,
    const float* __restrict__ wgt_list, float* __restrict__ out) {
    int e, xq, y;
    decode_work(blockIdx.x, e, xq, y);
    const int n_e = cnt[e];
    const int mBase = y * 128;
    if (mBase >= n_e) return;
    const int nBase = xq * 128;
    const int tid = threadIdx.x;

    __shared__ __attribute__((aligned(16))) ushort sA[128 * 32];
    __shared__ __attribute__((aligned(16))) ushort sB[128 * 32];
    __shared__ int sTok[128];
    __shared__ float sWgt[128];

    if (tid < 128) {
        int slot = mBase + tid;
        int cs = (slot < n_e) ? slot : 0;
        sTok[tid] = tok_list[e * T_TOK + cs];
        sWgt[tid] = wgt_list[e * T_TOK + cs];
    }
    __syncthreads();

    const int row0 = ofs[e] + mBase;
    const ushort* w2E = w2b + (size_t)e * (size_t)HD * ID;
    const ushort* aSrc[2];
    const ushort* bSrc[2];
#pragma unroll
    for (int i = 0; i < 2; i++) {
        int lin = i * 256 + tid;
        int ar = lin >> 2, ac = lin & 3;
        int rr = (mBase + ar < n_e) ? ar : 0;
        aSrc[i] = act + (size_t)(row0 + rr) * ID + ac * 8;
        int n = nBase + ar; if (n >= HD) n = HD - 1;
        bSrc[i] = w2E + (size_t)n * ID + ac * 8;
    }

    const int wave = tid >> 6, lane = tid & 63;
    const int wm = (wave >> 1) * 64, wn = (wave & 1) * 64;
    const int ln = lane & 15, quad = lane >> 4;

    floatx4 acc[4][4];
#pragma unroll
    for (int mi = 0; mi < 4; mi++)
#pragma unroll
        for (int ni = 0; ni < 4; ni++) acc[mi][ni] = (floatx4){0.f, 0.f, 0.f, 0.f};

    for (int k0 = 0; k0 < ID; k0 += 32) {
#pragma unroll
        for (int i = 0; i < 2; i++) {
            int lin = i * 256 + tid;
            gload_lds16(aSrc[i] + k0, &sA[lin * 8]);
            gload_lds16(bSrc[i] + k0, &sB[lin * 8]);
        }
        __syncthreads();

        short8 af[4], bf[4];
#pragma unroll
        for (int mi = 0; mi < 4; mi++)
            af[mi] = *(const short8*)&sA[(wm + mi * 16 + ln) * 32 + quad * 8];
#pragma unroll
        for (int ni = 0; ni < 4; ni++)
            bf[ni] = *(const short8*)&sB[(wn + ni * 16 + ln) * 32 + quad * 8];
#pragma unroll
        for (int mi = 0; mi < 4; mi++)
#pragma unroll
            for (int ni = 0; ni < 4; ni++)
                acc[mi][ni] = __builtin_amdgcn_mfma_f32_16x16x32_bf16(
                    af[mi], bf[ni], acc[mi][ni], 0, 0, 0);
        __syncthreads();
    }

#pragma unroll
    for (int mi = 0; mi < 4; mi++) {
#pragma unroll
        for (int r = 0; r < 4; r++) {
            int ml = wm + mi * 16 + quad * 4 + r;
            if (mBase + ml >= n_e) continue;
            int token = sTok[ml];
            float wgt = sWgt[ml];
#pragma unroll
            for (int ni = 0; ni < 4; ni++) {
                int n = nBase + wn + ni * 16 + ln;
                if (n < HD) {
                    float v = (acc[mi][ni][r] + b2[e * HD + n]) * wgt;
                    atomicAdd(&out[(size_t)token * HD + n], v);
                }
            }
        }
    }
}

// ================================================================ FALLBACK PATH
// (fp32-weight kernels; used only if workspace is too small for bf16 copies)
#define LDS_S 40  // padded row stride in bf16 elems
__global__ __launch_bounds__(256, 2) void expert_gu_kernel(
    const ushort* __restrict__ xb, const float* __restrict__ wg,
    const float* __restrict__ bg, const float* __restrict__ wu,
    const float* __restrict__ bu, const int* __restrict__ cnt,
    const int* __restrict__ ofs, const int* __restrict__ tok_list,
    ushort* __restrict__ act) {
    const int e = blockIdx.z;
    const int n_e = cnt[e];
    const int mBase = blockIdx.y * 128;
    if (mBase >= n_e) return;
    const int nBase = blockIdx.x * 128;
    const int tid = threadIdx.x;

    __shared__ ushort sA[128 * LDS_S];
    __shared__ ushort sBg[128 * LDS_S];
    __shared__ ushort sBu[128 * LDS_S];
    __shared__ int sTok[128];

    if (tid < 128) {
        int slot = mBase + tid;
        sTok[tid] = tok_list[e * T_TOK + (slot < n_e ? slot : 0)];
    }
    __syncthreads();

    const int wave = tid >> 6, lane = tid & 63;
    const int wm = (wave >> 1) * 64, wn = (wave & 1) * 64;
    const int ln = lane & 15, quad = lane >> 4;

    floatx4 accG[4][4], accU[4][4];
#pragma unroll
    for (int mi = 0; mi < 4; mi++)
#pragma unroll
        for (int ni = 0; ni < 4; ni++) {
            accG[mi][ni] = (floatx4){0.f, 0.f, 0.f, 0.f};
            accU[mi][ni] = (floatx4){0.f, 0.f, 0.f, 0.f};
        }

    const float* wgE = wg + (size_t)e * ID * HD;
    const float* wuE = wu + (size_t)e * ID * HD;

    for (int k0 = 0; k0 < HD; k0 += 32) {
#pragma unroll
        for (int r = 0; r < 2; r++) {
            int lin = r * 256 + tid;
            int ar = lin >> 2, ac = lin & 3;
            uint4 v = *(const uint4*)(xb + (size_t)sTok[ar] * HD + k0 + ac * 8);
            *(uint4*)&sA[ar * LDS_S + ac * 8] = v;
        }
#pragma unroll
        for (int r = 0; r < 4; r++) {
            int c = r * 256 + tid;
            int brow = c >> 3, bc = c & 7;
            int n = nBase + brow; if (n >= ID) n = ID - 1;
            float4 g4 = *(const float4*)(wgE + (size_t)n * HD + k0 + bc * 4);
            float4 u4 = *(const float4*)(wuE + (size_t)n * HD + k0 + bc * 4);
            ushort4 gg, uu;
            gg.x = f32_bf16(g4.x); gg.y = f32_bf16(g4.y);
            gg.z = f32_bf16(g4.z); gg.w = f32_bf16(g4.w);
            uu.x = f32_bf16(u4.x); uu.y = f32_bf16(u4.y);
            uu.z = f32_bf16(u4.z); uu.w = f32_bf16(u4.w);
            *(ushort4*)&sBg[brow * LDS_S + bc * 4] = gg;
            *(ushort4*)&sBu[brow * LDS_S + bc * 4] = uu;
        }
        __syncthreads();
        short8 af[4], bgf[4], buf_[4];
#pragma unroll
        for (int mi = 0; mi < 4; mi++)
            af[mi] = *(const short8*)&sA[(wm + mi * 16 + ln) * LDS_S + quad * 8];
#pragma unroll
        for (int ni = 0; ni < 4; ni++) {
            bgf[ni] = *(const short8*)&sBg[(wn + ni * 16 + ln) * LDS_S + quad * 8];
            buf_[ni] = *(const short8*)&sBu[(wn + ni * 16 + ln) * LDS_S + quad * 8];
        }
#pragma unroll
        for (int mi = 0; mi < 4; mi++)
#pragma unroll
            for (int ni = 0; ni < 4; ni++) {
                accG[mi][ni] = __builtin_amdgcn_mfma_f32_16x16x32_bf16(
                    af[mi], bgf[ni], accG[mi][ni], 0, 0, 0);
                accU[mi][ni] = __builtin_amdgcn_mfma_f32_16x16x32_bf16(
                    af[mi], buf_[ni], accU[mi][ni], 0, 0, 0);
            }
        __syncthreads();
    }

    const int row0 = ofs[e] + mBase;
#pragma unroll
    for (int mi = 0; mi < 4; mi++) {
#pragma unroll
        for (int r = 0; r < 4; r++) {
            int ml = wm + mi * 16 + quad * 4 + r;
            if (mBase + ml >= n_e) continue;
#pragma unroll
            for (int ni = 0; ni < 4; ni++) {
                int n = nBase + wn + ni * 16 + ln;
                if (n < ID) {
                    float g = accG[mi][ni][r] + bg[e * ID + n];
                    float u = accU[mi][ni][r] + bu[e * ID + n];
                    g = fminf(g, LIMIT);
                    u = fminf(fmaxf(u, -LIMIT), LIMIT);
                    float sg = 1.0f / (1.0f + __expf(-ALPHA * g));
                    float a = (u + 1.0f) * (g * sg);
                    act[(size_t)(row0 + ml) * ID + n] = f32_bf16(a);
                }
            }
        }
    }
}

__global__ __launch_bounds__(256, 2) void expert_down_kernel(
    const ushort* __restrict__ act, const float* __restrict__ w2,
    const float* __restrict__ b2, const int* __restrict__ cnt,
    const int* __restrict__ ofs, const int* __restrict__ tok_list,
    const float* __restrict__ wgt_list, float* __restrict__ out) {
    const int e = blockIdx.z;
    const int n_e = cnt[e];
    const int mBase = blockIdx.y * 128;
    if (mBase >= n_e) return;
    const int nBase = blockIdx.x * 128;
    const int tid = threadIdx.x;

    __shared__ ushort sA[128 * LDS_S];
    __shared__ ushort sB[128 * LDS_S];
    __shared__ int sTok[128];
    __shared__ float sWgt[128];

    if (tid < 128) {
        int slot = mBase + tid;
        int cs = (slot < n_e) ? slot : 0;
        sTok[tid] = tok_list[e * T_TOK + cs];
        sWgt[tid] = wgt_list[e * T_TOK + cs];
    }
    __syncthreads();

    const int wave = tid >> 6, lane = tid & 63;
    const int wm = (wave >> 1) * 64, wn = (wave & 1) * 64;
    const int ln = lane & 15, quad = lane >> 4;
    const int row0 = ofs[e] + mBase;

    floatx4 acc[4][4];
#pragma unroll
    for (int mi = 0; mi < 4; mi++)
#pragma unroll
        for (int ni = 0; ni < 4; ni++) acc[mi][ni] = (floatx4){0.f, 0.f, 0.f, 0.f};

    const float* w2E = w2 + (size_t)e * HD * ID;

    for (int k0 = 0; k0 < ID; k0 += 32) {
#pragma unroll
        for (int r = 0; r < 2; r++) {
            int lin = r * 256 + tid;
            int ar = lin >> 2, ac = lin & 3;
            int rr = (mBase + ar < n_e) ? ar : 0;
            uint4 v = *(const uint4*)(act + (size_t)(row0 + rr) * ID + k0 + ac * 8);
            *(uint4*)&sA[ar * LDS_S + ac * 8] = v;
        }
#pragma unroll
        for (int r = 0; r < 4; r++) {
            int c = r * 256 + tid;
            int brow = c >> 3, bc = c & 7;
            int n = nBase + brow; if (n >= HD) n = HD - 1;
            float4 b4 = *(const float4*)(w2E + (size_t)n * ID + k0 + bc * 4);
            ushort4 bb;
            bb.x = f32_bf16(b4.x); bb.y = f32_bf16(b4.y);
            bb.z = f32_bf16(b4.z); bb.w = f32_bf16(b4.w);
            *(ushort4*)&sB[brow * LDS_S + bc * 4] = bb;
        }
        __syncthreads();
        short8 af[4], bf[4];
#pragma unroll
        for (int mi = 0; mi < 4; mi++)
            af[mi] = *(const short8*)&sA[(wm + mi * 16 + ln) * LDS_S + quad * 8];
#pragma unroll
        for (int ni = 0; ni < 4; ni++)
            bf[ni] = *(const short8*)&sB[(wn + ni * 16 + ln) * LDS_S + quad * 8];
#pragma unroll
        for (int mi = 0; mi < 4; mi++)
#pragma unroll
            for (int ni = 0; ni < 4; ni++)
                acc[mi][ni] = __builtin_amdgcn_mfma_f32_16x16x32_bf16(
                    af[mi], bf[ni], acc[mi][ni], 0, 0, 0);
        __syncthreads();
    }

#pragma unroll
    for (int mi = 0; mi < 4; mi++) {
#pragma unroll
        for (int r = 0; r < 4; r++) {
            int ml = wm + mi * 16 + quad * 4 + r;
            if (mBase + ml >= n_e) continue;
            int token = sTok[ml];
            float wgt = sWgt[ml];
#pragma unroll
            for (int ni = 0; ni < 4; ni++) {
                int n = nBase + wn + ni * 16 + ln;
                if (n < HD) {
                    float v = (acc[mi][ni][r] + b2[e * HD + n]) * wgt;
                    atomicAdd(&out[(size_t)token * HD + n], v);
                }
            }
        }
    }
}

// ---------------------------------------------------------------- launch
extern "C" void kernel_launch(void* const* d_in, const int* in_sizes, int n_in,
                              void* d_out, int out_size, void* d_ws, size_t ws_size,
                              hipStream_t stream) {
    const float* x  = (const float*)d_in[0];
    const float* wr = (const float*)d_in[1];
    const float* br = (const float*)d_in[2];
    const float* wg = (const float*)d_in[3];
    const float* bg = (const float*)d_in[4];
    const float* wu = (const float*)d_in[5];
    const float* bu = (const float*)d_in[6];
    const float* w2 = (const float*)d_in[7];
    const float* b2 = (const float*)d_in[8];
    float* out = (float*)d_out;

    // workspace layout
    char* ws = (char*)d_ws;
    int*    cnt      = (int*)ws;                        // 32 B used
    int*    ofs      = (int*)(ws + 256);
    int*    tok_list = (int*)(ws + 512);                // E*T*4   = 65536
    float*  wgt_list = (float*)(ws + 512 + 65536);      // E*T*4   = 65536
    ushort* xb       = (ushort*)(ws + 131584);          // T*H*2   = 11796480
    ushort* act      = (ushort*)(ws + 131584 + 11796480);          // 8192*I*2 = 47185920
    // bf16 weight copies: 3 x 132710400
    const size_t W_ELEMS = (size_t)NE * ID * HD;        // 66,355,200 per tensor
    ushort* wgb = (ushort*)(ws + 59113984);
    ushort* wub = (ushort*)(ws + 59113984 + 132710400);
    ushort* w2b = (ushort*)(ws + 59113984 + 2ull * 132710400);
    const size_t NEED = 59113984ull + 3ull * 132710400ull;  // 457,245,184 B
    // no-atomic path extras: token->slot map + packed y rows (fp32)
    int*   t2s = (int*)(ws + NEED);                      // T*K*4 = 32768
    float* yws = (float*)(ws + NEED + 32768);            // 8192*HD*4 = 94,371,840
    const size_t NEED3 = NEED + 32768ull + 94371840ull;  // 551,649,792 B

    const bool bf16_path = (ws_size >= NEED);
    const bool na_path   = (ws_size >= NEED3);

    hipMemsetAsync(out, 0, (size_t)T_TOK * HD * sizeof(float), stream);
    hipMemsetAsync(cnt, 0, NE * sizeof(int), stream);

    cvt_x_kernel<<<(T_TOK * HD) / 4 / 256, 256, 0, stream>>>(x, xb);
    router_kernel<<<T_TOK, 256, 0, stream>>>(x, wr, br, cnt, tok_list, wgt_list,
                                             na_path ? t2s : nullptr);
    offsets_kernel<<<1, 64, 0, stream>>>(cnt, ofs);

    if (bf16_path) {
        const int n4 = (int)(W_ELEMS / 4);  // 16,588,800
        cvt_w_kernel<<<8192, 256, 0, stream>>>(wg, wgb, n4);
        cvt_w_kernel<<<8192, 256, 0, stream>>>(wu, wub, n4);
        cvt_w_kernel<<<8192, 256, 0, stream>>>(w2, w2b, n4);

        expert_gu2_kernel<<<NWG, 256, 0, stream>>>(xb, wgb, bg, wub, bu, cnt, ofs,
                                                   tok_list, act);
        if (na_path) {
            expert_down2_na_kernel<<<NWG, 256, 0, stream>>>(act, w2b, b2, cnt, ofs,
                                                            wgt_list, yws);
            combine_kernel<<<T_TOK, 256, 0, stream>>>(yws, t2s, ofs, out);
        } else {
            expert_down2_kernel<<<NWG, 256, 0, stream>>>(act, w2b, b2, cnt, ofs,
                                                         tok_list, wgt_list, out);
        }
    } else {
        dim3 g1((ID + 127) / 128, T_TOK / 128, NE);
        expert_gu_kernel<<<g1, 256, 0, stream>>>(xb, wg, bg, wu, bu, cnt, ofs,
                                                 tok_list, act);
        dim3 g2((HD + 127) / 128, T_TOK / 128, NE);
        expert_down_kernel<<<g2, 256, 0, stream>>>(act, w2, b2, cnt, ofs, tok_list,
                                                   wgt_list, out);
    }
}